// Round 12
// baseline (383.391 us; speedup 1.0000x reference)
//
#include <hip/hip_runtime.h>
#include <hip/hip_bf16.h>
#include <math.h>

#define BDIM 512
typedef __hip_bfloat16 bf16;

// Device buffers confirmed float32.
// Dead-end ledger (r4-r8): BDIM=1024 -> 64-VGPR pin + spills; 2 blocks/CU never
// co-resides; LSTM weights from global -> L1-thrash; Enc in global -> latency.
// r10: Enc plane stride must be != 0 mod 32 (2120 == 8 mod 32 -> free 2-way).
// r12: decoder A->LSTM hand-off via same-wave __shfl (bit-exact, kills 36 LDS
// instr/lane/step); encoder gdmat prefetched one step ahead.

__device__ __forceinline__ float sigm(float v)  { return 1.0f / (1.0f + __expf(-v)); }
__device__ __forceinline__ float ftanh(float v) { return 1.0f - 2.0f / (__expf(2.0f * v) + 1.0f); }
__device__ __forceinline__ float mod360(float v){ return v - 360.0f * floorf(v * (1.0f / 360.0f)); }

__device__ __forceinline__ float atan2_deg(float y, float x) {
  float ax = fabsf(x), ay = fabsf(y);
  float mx = fmaxf(ax, ay), mn = fminf(ax, ay);
  float r = mn / fmaxf(mx, 1e-30f);
  float r2 = r * r;
  float a = r * (0.99997726f + r2 * (-0.33262347f + r2 * (0.19354346f +
            r2 * (-0.11643287f + r2 * (0.05265332f - r2 * 0.01172120f)))));
  if (ay > ax) a = 1.5707963267948966f - a;
  if (x < 0.0f) a = 3.141592653589793f - a;
  a = copysignf(a, y);
  return a * 57.29577951308232f;
}

struct Smem {
  alignas(16) float H[2][64][32];  // double-buffered carry h
  alignas(16) float C[64][32];     // carry c (own-rows only)
  alignas(16) float HC[64][36];    // lstm out (stride 36: f4-aligned, min-conflict)
  union EU {
    float EmbCtx[64][32];          // encoder E-slot unused now; decoder Ctx (temporal->wtemp)
    struct { float Pos[64][2]; float Head[64]; } sp;  // slow path only
  };
  alignas(16) EU u;
  float Enc[8][2120];              // [t][p*33+k]; 2120 == 8 mod 32 (bank spread!)
  alignas(16) float W[64][68];     // spatial weights
  float RS[64];
  alignas(8) bf16 WtTT[32][68];    // W_temp row-major bf16, padded rows
  alignas(16) float WL[128][36];   // LSTM hidden weights (K=32; E folded out)
  float VxE0[128], VxE1[128];      // folded x-coefficients: Wih . Wemb[:,f]
  float VxD0[128], VxD1[128];
  float BsumE[128], BsumD[128];    // bih + bhh + Wih.bemb
  float Dom[144];
  float Btemp[32];
  float Wout[2][32];
  float Bout[2];
  float MaskF[8][64];
  unsigned int MaskBits[64];
  float Xprev[64][2];
  float Xout[2][64][2];
  float MV[4];
};
static_assert(sizeof(Smem) <= 160 * 1024, "LDS over budget");

// Encoder LSTM: acts from LDS (cross-barrier producer). thread (k,pg) -> 4 gates x 4 peds.
__device__ __forceinline__ void lstm2(int tid, Smem& s,
    const float (*Hin)[32], const float* __restrict__ bsum,
    const float* __restrict__ vx0, const float* __restrict__ vx1) {
  const int k = tid & 31, pg = tid >> 5, p0 = pg * 4;
  const float4* W0 = (const float4*)s.WL[k];
  const float4* W1 = (const float4*)s.WL[32 + k];
  const float4* W2 = (const float4*)s.WL[64 + k];
  const float4* W3 = (const float4*)s.WL[96 + k];
  const float v00 = vx0[k],      v01 = vx1[k];
  const float v10 = vx0[32 + k], v11 = vx1[32 + k];
  const float v20 = vx0[64 + k], v21 = vx1[64 + k];
  const float v30 = vx0[96 + k], v31 = vx1[96 + k];
  const float b0 = bsum[k], b1 = bsum[32 + k], b2 = bsum[64 + k], b3 = bsum[96 + k];
  float a0[4], a1[4], a2[4], a3[4];
  #pragma unroll
  for (int pi = 0; pi < 4; ++pi) {
    const int p = p0 + pi;
    const float x0 = s.Xprev[p][0], x1 = s.Xprev[p][1];
    a0[pi] = b0 + x0 * v00 + x1 * v01;
    a1[pi] = b1 + x0 * v10 + x1 * v11;
    a2[pi] = b2 + x0 * v20 + x1 * v21;
    a3[pi] = b3 + x0 * v30 + x1 * v31;
  }
  #pragma unroll
  for (int m4 = 0; m4 < 8; ++m4) {
    float4 w0 = W0[m4], w1 = W1[m4], w2 = W2[m4], w3 = W3[m4];
    #pragma unroll
    for (int pi = 0; pi < 4; ++pi) {
      float4 hv = ((const float4*)Hin[p0 + pi])[m4];
      a0[pi] += hv.x * w0.x + hv.y * w0.y + hv.z * w0.z + hv.w * w0.w;
      a1[pi] += hv.x * w1.x + hv.y * w1.y + hv.z * w1.z + hv.w * w1.w;
      a2[pi] += hv.x * w2.x + hv.y * w2.y + hv.z * w2.z + hv.w * w2.w;
      a3[pi] += hv.x * w3.x + hv.y * w3.y + hv.z * w3.z + hv.w * w3.w;
    }
  }
  #pragma unroll
  for (int pi = 0; pi < 4; ++pi) {
    const int p = p0 + pi;
    float iv = sigm(a0[pi]), fv = sigm(a1[pi]);
    float gv = ftanh(a2[pi]), ov = sigm(a3[pi]);
    float cn = fv * s.C[p][k] + iv * gv;
    s.C[p][k] = cn;
    s.HC[p][k] = ov * ftanh(cn);
  }
}

// Decoder LSTM: acts received via same-wave shuffle from phase A's registers.
// A-lane (h|m) holds emb[pi] = Emb[wave*8 + h*4 + pi][m]  (h = lane>>5, m = lane&31).
// LSTM lane (k,pg) needs acts[p0+pi][m] -> src lane = (tid&32) | m.  Bit-exact.
__device__ __forceinline__ void lstm2_shfl(int tid, Smem& s,
    const float emb[4], const float* __restrict__ bsum,
    const float* __restrict__ vx0, const float* __restrict__ vx1) {
  const int k = tid & 31, pg = tid >> 5, p0 = pg * 4;
  const int sbase = tid & 32;
  const float4* W0 = (const float4*)s.WL[k];
  const float4* W1 = (const float4*)s.WL[32 + k];
  const float4* W2 = (const float4*)s.WL[64 + k];
  const float4* W3 = (const float4*)s.WL[96 + k];
  const float v00 = vx0[k],      v01 = vx1[k];
  const float v10 = vx0[32 + k], v11 = vx1[32 + k];
  const float v20 = vx0[64 + k], v21 = vx1[64 + k];
  const float v30 = vx0[96 + k], v31 = vx1[96 + k];
  const float b0 = bsum[k], b1 = bsum[32 + k], b2 = bsum[64 + k], b3 = bsum[96 + k];
  float a0[4], a1[4], a2[4], a3[4];
  #pragma unroll
  for (int pi = 0; pi < 4; ++pi) {
    const int p = p0 + pi;
    const float x0 = s.Xprev[p][0], x1 = s.Xprev[p][1];
    a0[pi] = b0 + x0 * v00 + x1 * v01;
    a1[pi] = b1 + x0 * v10 + x1 * v11;
    a2[pi] = b2 + x0 * v20 + x1 * v21;
    a3[pi] = b3 + x0 * v30 + x1 * v31;
  }
  #pragma unroll
  for (int m4 = 0; m4 < 8; ++m4) {
    float4 w0 = W0[m4], w1 = W1[m4], w2 = W2[m4], w3 = W3[m4];
    #pragma unroll
    for (int pi = 0; pi < 4; ++pi) {
      const float hx = __shfl(emb[pi], sbase + m4 * 4 + 0);
      const float hy = __shfl(emb[pi], sbase + m4 * 4 + 1);
      const float hz = __shfl(emb[pi], sbase + m4 * 4 + 2);
      const float hw = __shfl(emb[pi], sbase + m4 * 4 + 3);
      a0[pi] += hx * w0.x + hy * w0.y + hz * w0.z + hw * w0.w;
      a1[pi] += hx * w1.x + hy * w1.y + hz * w1.z + hw * w1.w;
      a2[pi] += hx * w2.x + hy * w2.y + hz * w2.z + hw * w2.w;
      a3[pi] += hx * w3.x + hy * w3.y + hz * w3.z + hw * w3.w;
    }
  }
  #pragma unroll
  for (int pi = 0; pi < 4; ++pi) {
    const int p = p0 + pi;
    float iv = sigm(a0[pi]), fv = sigm(a1[pi]);
    float gv = ftanh(a2[pi]), ov = sigm(a3[pi]);
    float cn = fv * s.C[p][k] + iv * gv;
    s.C[p][k] = cn;
    s.HC[p][k] = ov * ftanh(cn);
  }
}

__global__ __launch_bounds__(BDIM, 2) void traj_fwd(
    const float* __restrict__ gx, const float* __restrict__ gdmat,
    const float* __restrict__ gbmat, const float* __restrict__ ghmat,
    const float* __restrict__ gimask,
    const float* __restrict__ gmean, const float* __restrict__ gvar,
    const float* __restrict__ gWemb, const float* __restrict__ gbemb,
    const float* __restrict__ gWihE, const float* __restrict__ gWhhE,
    const float* __restrict__ gbihE, const float* __restrict__ gbhhE,
    const float* __restrict__ gWihD, const float* __restrict__ gWhhD,
    const float* __restrict__ gbihD, const float* __restrict__ gbhhD,
    const float* __restrict__ gdom, const float* __restrict__ gWtemp,
    const float* __restrict__ gbtemp, const float* __restrict__ gWout,
    const float* __restrict__ gbout, float* __restrict__ gout)
{
  __shared__ Smem s;
  const int b = blockIdx.x, tid = threadIdx.x;

  // ================= PROLOGUE (one barrier) =================
  if (tid < 128) {   // E-fold: Vx = Wih.Wemb[:,f], bias += Wih.bemb
    float be = 0, bd = 0, e0 = 0, e1 = 0, d0 = 0, d1 = 0;
    #pragma unroll
    for (int k = 0; k < 16; ++k) {
      const float wE = gWihE[tid * 16 + k], wD = gWihD[tid * 16 + k];
      const float w0 = gWemb[k * 2 + 0], w1 = gWemb[k * 2 + 1], bb = gbemb[k];
      e0 += wE * w0; e1 += wE * w1; be += wE * bb;
      d0 += wD * w0; d1 += wD * w1; bd += wD * bb;
    }
    s.VxE0[tid] = e0; s.VxE1[tid] = e1;
    s.VxD0[tid] = d0; s.VxD1[tid] = d1;
    s.BsumE[tid] = gbihE[tid] + gbhhE[tid] + be;
    s.BsumD[tid] = gbihD[tid] + gbhhD[tid] + bd;
  }
  for (int i = tid; i < 2048; i += BDIM) {
    int kp = i >> 6, m = i & 63;
    s.WtTT[kp][m] = __float2bfloat16(gWtemp[i]);
  }
  for (int i = tid; i < 144; i += BDIM) s.Dom[i] = gdom[i];
  if (tid < 32) s.Btemp[tid] = gbtemp[tid];
  if (tid < 64) s.Wout[tid >> 5][tid & 31] = gWout[tid];
  if (tid < 2)  s.Bout[tid] = gbout[tid];
  if (tid < 4)  s.MV[tid] = (tid < 2) ? gmean[b * 2 + tid] : gvar[b * 2 + tid - 2];
  for (int i = tid; i < 512; i += BDIM) {
    int t = i >> 6, p = i & 63;
    s.MaskF[t][p] = gimask[(b * 64 + p) * 8 + t];
  }
  if (tid < 64) {
    const float4 m0 = *(const float4*)&gimask[(b * 64 + tid) * 8];
    const float4 m1 = *(const float4*)&gimask[(b * 64 + tid) * 8 + 4];
    unsigned int mb = 0;
    mb |= (m0.x > 0.0f) ? 1u : 0u;  mb |= (m0.y > 0.0f) ? 2u : 0u;
    mb |= (m0.z > 0.0f) ? 4u : 0u;  mb |= (m0.w > 0.0f) ? 8u : 0u;
    mb |= (m1.x > 0.0f) ? 16u : 0u; mb |= (m1.y > 0.0f) ? 32u : 0u;
    mb |= (m1.z > 0.0f) ? 64u : 0u; mb |= (m1.w > 0.0f) ? 128u : 0u;
    s.MaskBits[tid] = mb;
  }
  for (int idx = tid; idx < 128 * 32; idx += BDIM) {
    int j = idx >> 5, m = idx & 31;
    s.WL[j][m] = gWhhE[j * 32 + m];
  }
  for (int i = tid; i < 2048; i += BDIM) { s.H[0][i >> 5][i & 31] = 0.0f; s.C[i >> 5][i & 31] = 0.0f; }
  __syncthreads();

  bool uni = true;
  {
    const float d0 = s.Dom[0];
    for (int i = 0; i < 144; ++i) uni = uni && (s.Dom[i] == d0);
  }
  const float dom0 = s.Dom[0];

  // ================= ENCODER (2 barriers/iter, gdmat prefetched) =================
  const int enc_i = tid >> 3, enc_g = tid & 7, enc_j8 = enc_g * 8;
  float4 pf0, pf1;
  if (uni) {
    const int gb0 = ((b * 64 + enc_i) * 8 + 0) * 64 + enc_j8;
    pf0 = *(const float4*)&gdmat[gb0];
    pf1 = *(const float4*)&gdmat[gb0 + 4];
  }
  for (int t = 0; t < 8; ++t) {
    const int he = t & 1;
    {  // P1: W-build + rowsum shuffle + Xprev own-load
      const int i = enc_i, g = enc_g, j8 = enc_j8;
      const float mi = s.MaskF[t][i];
      float w[8];
      if (uni) {
        const float4 dv0 = pf0, dv1 = pf1;
        if (t < 7) {   // issue next step's loads now; arrive during LSTM+P3
          const int gbn = (((b * 64 + i) * 8 + (t + 1)) << 6) + j8;
          pf0 = *(const float4*)&gdmat[gbn];
          pf1 = *(const float4*)&gdmat[gbn + 4];
        }
        w[0] = fmaxf(dom0 - dv0.x, 0.0f) * mi * s.MaskF[t][j8 + 0];
        w[1] = fmaxf(dom0 - dv0.y, 0.0f) * mi * s.MaskF[t][j8 + 1];
        w[2] = fmaxf(dom0 - dv0.z, 0.0f) * mi * s.MaskF[t][j8 + 2];
        w[3] = fmaxf(dom0 - dv0.w, 0.0f) * mi * s.MaskF[t][j8 + 3];
        w[4] = fmaxf(dom0 - dv1.x, 0.0f) * mi * s.MaskF[t][j8 + 4];
        w[5] = fmaxf(dom0 - dv1.y, 0.0f) * mi * s.MaskF[t][j8 + 5];
        w[6] = fmaxf(dom0 - dv1.z, 0.0f) * mi * s.MaskF[t][j8 + 6];
        w[7] = fmaxf(dom0 - dv1.w, 0.0f) * mi * s.MaskF[t][j8 + 7];
      } else {
        #pragma unroll
        for (int c = 0; c < 8; ++c) {
          int gi = (((b * 64 + i) * 8 + t) << 6) + j8 + c;
          float dv = gdmat[gi], bv = gbmat[gi], hv = ghmat[gi];
          int ibn = (int)floorf(bv * (1.0f / 30.0f)); ibn = ibn < 0 ? 0 : (ibn > 11 ? 11 : ibn);
          int ihn = (int)floorf(hv * (1.0f / 30.0f)); ihn = ihn < 0 ? 0 : (ihn > 11 ? 11 : ihn);
          w[c] = fmaxf(s.Dom[ihn * 12 + ibn] - dv, 0.0f) * mi * s.MaskF[t][j8 + c];
        }
      }
      *(float4*)&s.W[i][j8]     = make_float4(w[0], w[1], w[2], w[3]);
      *(float4*)&s.W[i][j8 + 4] = make_float4(w[4], w[5], w[6], w[7]);
      float tot = ((w[0] + w[1]) + (w[2] + w[3])) + ((w[4] + w[5]) + (w[6] + w[7]));
      tot += __shfl_xor(tot, 1); tot += __shfl_xor(tot, 2); tot += __shfl_xor(tot, 4);
      if (g == 0) {
        s.RS[i] = 1.0f / (tot + 1e-8f);
        s.Xprev[i][0] = gx[((b * 64 + i) * 8 + t) * 2];
        s.Xprev[i][1] = gx[((b * 64 + i) * 8 + t) * 2 + 1];
      }
    }
    lstm2(tid, s, s.H[he], s.BsumE, s.VxE0, s.VxE1);
    __syncthreads();   // barA: HC all-rows visible to P3
    {  // P3: spatial attention + tanh -> H[he^1] own rows + Enc[t]
      const int k2 = tid & 31, ig = tid >> 5, i0 = ig * 4;
      float acc[4] = {};
      #pragma unroll
      for (int c = 0; c < 16; ++c) {
        float h0 = s.HC[c * 4 + 0][k2], h1 = s.HC[c * 4 + 1][k2];
        float h2 = s.HC[c * 4 + 2][k2], h3 = s.HC[c * 4 + 3][k2];
        #pragma unroll
        for (int ii = 0; ii < 4; ++ii) {
          float4 wv = *(const float4*)&s.W[i0 + ii][c * 4];
          acc[ii] += wv.x * h0 + wv.y * h1 + wv.z * h2 + wv.w * h3;
        }
      }
      #pragma unroll
      for (int ii = 0; ii < 4; ++ii) {
        int i = i0 + ii;
        float v = ftanh(acc[ii] * s.RS[i]);
        s.H[he ^ 1][i][k2] = v;
        s.Enc[t][i * 33 + k2] = v;
      }
    }
    __syncthreads();   // barB: HC-all-reads done before next P2 writes HC
  }

  // ================= DECODER START =================
  for (int idx = tid; idx < 128 * 32; idx += BDIM) {
    int j = idx >> 5, m = idx & 31;
    s.WL[j][m] = gWhhD[j * 32 + m];
  }
  for (int i = tid; i < 2048; i += BDIM) s.C[i >> 5][i & 31] = 0.0f;
  if (tid < 128) {
    int p = tid >> 1, f = tid & 1;
    s.Xprev[p][f] = gx[((b * 64 + p) * 8 + 7) * 2 + f];
  }
  __syncthreads();
  // W/RS persist from encoder t=7; h_enc is in H[0].

  // ================= DECODER (1 barrier/step on fast path) =================
  for (int sd = 0; sd < 12; ++sd) {
    const int cur = sd & 1;
    float emb[4];
    {  // A: spatial attn on H[cur] -> emb kept in registers (shuffle hand-off)
      const int k2 = tid & 31, ig = tid >> 5, i0 = ig * 4;
      float acc[4] = {};
      #pragma unroll
      for (int c = 0; c < 16; ++c) {
        float h0 = s.H[cur][c * 4 + 0][k2], h1 = s.H[cur][c * 4 + 1][k2];
        float h2 = s.H[cur][c * 4 + 2][k2], h3 = s.H[cur][c * 4 + 3][k2];
        #pragma unroll
        for (int ii = 0; ii < 4; ++ii) {
          float4 wv = *(const float4*)&s.W[i0 + ii][c * 4];
          acc[ii] += wv.x * h0 + wv.y * h1 + wv.z * h2 + wv.w * h3;
        }
      }
      #pragma unroll
      for (int ii = 0; ii < 4; ++ii)
        emb[ii] = ftanh(acc[ii] * s.RS[i0 + ii]);
    }
    lstm2_shfl(tid, s, emb, s.BsumD, s.VxD0, s.VxD1);
    {  // temporal: thread = (p = tid>>3 own, t8 = tid&7)
      const int p = tid >> 3, t8 = tid & 7;
      const float4* h4p = (const float4*)s.HC[p];   // 144B rows: 16B-aligned
      const float* enr = &s.Enc[t8][p * 33];
      float sc = 0.0f;
      #pragma unroll
      for (int c = 0; c < 8; ++c) {
        const float4 h4 = h4p[c];
        sc += h4.x * enr[c * 4 + 0] + h4.y * enr[c * 4 + 1]
            + h4.z * enr[c * 4 + 2] + h4.w * enr[c * 4 + 3];
      }
      sc *= 0.17677669529663687f;
      sc = ((s.MaskBits[p] >> t8) & 1u) ? sc : -1e9f;
      float mx = sc;
      mx = fmaxf(mx, __shfl_xor(mx, 1));
      mx = fmaxf(mx, __shfl_xor(mx, 2));
      mx = fmaxf(mx, __shfl_xor(mx, 4));
      float e = __expf(sc - mx);
      float den = e;
      den += __shfl_xor(den, 1);
      den += __shfl_xor(den, 2);
      den += __shfl_xor(den, 4);
      float a = e / den;
      float av[8];
      #pragma unroll
      for (int tt = 0; tt < 8; ++tt) av[tt] = __shfl(a, tt, 8);
      const int kb = t8 * 4;
      float c0 = 0, c1 = 0, c2 = 0, c3 = 0;
      #pragma unroll
      for (int tt = 0; tt < 8; ++tt) {
        const float* er = &s.Enc[tt][p * 33 + kb];
        c0 += av[tt] * er[0]; c1 += av[tt] * er[1];
        c2 += av[tt] * er[2]; c3 += av[tt] * er[3];
      }
      *(float4*)&s.u.EmbCtx[p][kb] = make_float4(c0, c1, c2, c3);
    }
    {  // wtemp + fused x_out
      const int kp = tid & 31, pg = tid >> 5;
      const uint2* wrow = (const uint2*)s.WtTT[kp];
      float acc[4];
      #pragma unroll
      for (int pi = 0; pi < 4; ++pi) acc[pi] = s.Btemp[kp];
      #pragma unroll
      for (int mc = 0; mc < 16; ++mc) {
        const uint2 w2 = wrow[mc];
        const float f0 = __uint_as_float(w2.x << 16);
        const float f1 = __uint_as_float(w2.x & 0xFFFF0000u);
        const float f2 = __uint_as_float(w2.y << 16);
        const float f3 = __uint_as_float(w2.y & 0xFFFF0000u);
        #pragma unroll
        for (int pi = 0; pi < 4; ++pi) {
          const int p = pg * 4 + pi;
          const float4 av = (mc < 8) ? *(const float4*)&s.u.EmbCtx[p][mc * 4]
                                     : *(const float4*)&s.HC[p][(mc - 8) * 4];
          acc[pi] += av.x * f0 + av.y * f1 + av.z * f2 + av.w * f3;
        }
      }
      float r0[4], r1[4];
      #pragma unroll
      for (int pi = 0; pi < 4; ++pi) {
        float hv = ftanh(acc[pi]);
        s.H[cur ^ 1][pg * 4 + pi][kp] = hv;
        r0[pi] = hv * s.Wout[0][kp];
        r1[pi] = hv * s.Wout[1][kp];
      }
      #pragma unroll
      for (int st = 1; st < 32; st <<= 1) {
        #pragma unroll
        for (int pi = 0; pi < 4; ++pi) {
          r0[pi] += __shfl_xor(r0[pi], st);
          r1[pi] += __shfl_xor(r1[pi], st);
        }
      }
      if (kp == 0) {
        const int p0 = pg * 4;
        float* go = &gout[((b * 64 + p0) * 12 + sd) * 2];
        #pragma unroll
        for (int pi = 0; pi < 4; ++pi) {
          float vx = ftanh(r0[pi] + s.Bout[0]);
          float vy = ftanh(r1[pi] + s.Bout[1]);
          s.Xout[cur][p0 + pi][0] = vx; s.Xout[cur][p0 + pi][1] = vy;
          go[pi * 24] = vx; go[pi * 24 + 1] = vy;
        }
      }
    }
    __syncthreads();   // bar1: Xout[cur] + H[cur^1] visible to all
    if (sd < 11) {
      if (uni) {
        const int i = tid >> 3, g = tid & 7, j8 = g * 8;
        const float v0 = s.MV[2], v1 = s.MV[3];
        const float xi0 = s.Xout[cur][i][0], xi1 = s.Xout[cur][i][1];
        const float mi = s.MaskF[7][i];
        float w[8];
        #pragma unroll
        for (int c = 0; c < 8; ++c) {
          const int j = j8 + c;
          float rx = (s.Xout[cur][j][0] - xi0) * v0;
          float ry = (s.Xout[cur][j][1] - xi1) * v1;
          float dist = sqrtf(rx * rx + ry * ry + 1e-12f);
          w[c] = fmaxf(dom0 - dist, 0.0f) * mi * s.MaskF[7][j];
        }
        *(float4*)&s.W[i][j8]     = make_float4(w[0], w[1], w[2], w[3]);
        *(float4*)&s.W[i][j8 + 4] = make_float4(w[4], w[5], w[6], w[7]);
        float tot = ((w[0] + w[1]) + (w[2] + w[3])) + ((w[4] + w[5]) + (w[6] + w[7]));
        tot += __shfl_xor(tot, 1); tot += __shfl_xor(tot, 2); tot += __shfl_xor(tot, 4);
        if (g == 0) {
          s.RS[i] = 1.0f / (tot + 1e-8f);
          s.Xprev[i][0] = s.Xout[cur][i][0];
          s.Xprev[i][1] = s.Xout[cur][i][1];
        }
      } else {
        if (tid < 64) {
          const int p = tid;
          float m0 = s.MV[0], m1 = s.MV[1], v0 = s.MV[2], v1 = s.MV[3];
          float px = s.Xout[cur][p][0] * v0 + m0, py = s.Xout[cur][p][1] * v1 + m1;
          float qx = s.Xprev[p][0] * v0 + m0, qy = s.Xprev[p][1] * v1 + m1;
          s.u.sp.Head[p] = mod360(atan2_deg(py - qy, px - qx));
          s.u.sp.Pos[p][0] = px; s.u.sp.Pos[p][1] = py;
        }
        __syncthreads();
        const int i = tid >> 3, g = tid & 7, j8 = g * 8;
        const float mi = s.MaskF[7][i], hi = s.u.sp.Head[i];
        const float pix = s.u.sp.Pos[i][0], piy = s.u.sp.Pos[i][1];
        float w[8];
        #pragma unroll
        for (int c = 0; c < 8; ++c) {
          const int j = j8 + c;
          float rx = s.u.sp.Pos[j][0] - pix;
          float ry = s.u.sp.Pos[j][1] - piy;
          float dist = sqrtf(rx * rx + ry * ry + 1e-12f);
          float rb = mod360(atan2_deg(ry, rx) - hi);
          float rh = mod360(s.u.sp.Head[j] - hi);
          int ibn = (int)floorf(rb * (1.0f / 30.0f)); ibn = ibn < 0 ? 0 : (ibn > 11 ? 11 : ibn);
          int ihn = (int)floorf(rh * (1.0f / 30.0f)); ihn = ihn < 0 ? 0 : (ihn > 11 ? 11 : ihn);
          w[c] = fmaxf(s.Dom[ihn * 12 + ibn] - dist, 0.0f) * mi * s.MaskF[7][j];
        }
        *(float4*)&s.W[i][j8]     = make_float4(w[0], w[1], w[2], w[3]);
        *(float4*)&s.W[i][j8 + 4] = make_float4(w[4], w[5], w[6], w[7]);
        float tot = ((w[0] + w[1]) + (w[2] + w[3])) + ((w[4] + w[5]) + (w[6] + w[7]));
        tot += __shfl_xor(tot, 1); tot += __shfl_xor(tot, 2); tot += __shfl_xor(tot, 4);
        if (g == 0) {
          s.RS[i] = 1.0f / (tot + 1e-8f);
          s.Xprev[i][0] = s.Xout[cur][i][0];
          s.Xprev[i][1] = s.Xout[cur][i][1];
        }
        __syncthreads();
      }
    }
  }
}

extern "C" void kernel_launch(void* const* d_in, const int* in_sizes, int n_in,
                              void* d_out, int out_size, void* d_ws, size_t ws_size,
                              hipStream_t stream) {
  (void)in_sizes; (void)n_in; (void)d_ws; (void)ws_size; (void)out_size;
  traj_fwd<<<512, BDIM, 0, stream>>>(
      (const float*)d_in[0], (const float*)d_in[1], (const float*)d_in[2],
      (const float*)d_in[3], (const float*)d_in[4],
      /* d_in[5] output_mask, d_in[6] scene unused */
      (const float*)d_in[7], (const float*)d_in[8],
      (const float*)d_in[9], (const float*)d_in[10],
      (const float*)d_in[11], (const float*)d_in[12],
      (const float*)d_in[13], (const float*)d_in[14],
      (const float*)d_in[15], (const float*)d_in[16],
      (const float*)d_in[17], (const float*)d_in[18],
      (const float*)d_in[19], (const float*)d_in[20],
      (const float*)d_in[21], (const float*)d_in[22], (const float*)d_in[23],
      (float*)d_out);
}

// Round 13
// 359.391 us; speedup vs baseline: 1.0668x; 1.0668x over previous
//
#include <hip/hip_runtime.h>
#include <hip/hip_bf16.h>
#include <math.h>

#define BDIM 512
typedef __hip_bfloat16 bf16;

// Device buffers confirmed float32.
// Dead-end ledger (r4-r8, r12): BDIM=1024 -> 64-VGPR pin + spills; 2 blocks/CU
// never co-resides; LSTM weights from global -> L1-thrash; Enc in global ->
// latency; LDS->__shfl conversion -> moves work onto the saturated VALU pipe
// (r12: -23us regression). r10: Enc plane stride must be != 0 mod 32
// (2120 == 8 mod 32 -> free 2-way). This is r11, the measured optimum.

__device__ __forceinline__ float sigm(float v)  { return 1.0f / (1.0f + __expf(-v)); }
__device__ __forceinline__ float ftanh(float v) { return 1.0f - 2.0f / (__expf(2.0f * v) + 1.0f); }
__device__ __forceinline__ float mod360(float v){ return v - 360.0f * floorf(v * (1.0f / 360.0f)); }

__device__ __forceinline__ float atan2_deg(float y, float x) {
  float ax = fabsf(x), ay = fabsf(y);
  float mx = fmaxf(ax, ay), mn = fminf(ax, ay);
  float r = mn / fmaxf(mx, 1e-30f);
  float r2 = r * r;
  float a = r * (0.99997726f + r2 * (-0.33262347f + r2 * (0.19354346f +
            r2 * (-0.11643287f + r2 * (0.05265332f - r2 * 0.01172120f)))));
  if (ay > ax) a = 1.5707963267948966f - a;
  if (x < 0.0f) a = 3.141592653589793f - a;
  a = copysignf(a, y);
  return a * 57.29577951308232f;
}

struct Smem {
  alignas(16) float H[2][64][32];  // double-buffered carry h
  alignas(16) float C[64][32];     // carry c (own-rows only)
  alignas(16) float HC[64][36];    // lstm out (stride 36: f4-aligned, min-conflict)
  union EU {
    float EmbCtx[64][32];          // Emb (A->LSTM) then Ctx (temporal->wtemp)
    struct { float Pos[64][2]; float Head[64]; } sp;  // slow path only
  };
  alignas(16) EU u;
  float Enc[8][2120];              // [t][p*33+k]; 2120 == 8 mod 32 (bank spread!)
  alignas(16) float W[64][68];     // spatial weights
  float RS[64];
  alignas(8) bf16 WtTT[32][68];    // W_temp row-major bf16, padded rows
  alignas(16) float WL[128][36];   // LSTM hidden weights (K=32; E folded out)
  float VxE0[128], VxE1[128];      // folded x-coefficients: Wih . Wemb[:,f]
  float VxD0[128], VxD1[128];
  float BsumE[128], BsumD[128];    // bih + bhh + Wih.bemb
  float Dom[144];
  float Btemp[32];
  float Wout[2][32];
  float Bout[2];
  float MaskF[8][64];
  unsigned int MaskBits[64];
  float Xprev[64][2];
  float Xout[2][64][2];
  float MV[4];
};
static_assert(sizeof(Smem) <= 160 * 1024, "LDS over budget");

// LSTM: thread (k=tid&31, pg=tid>>5) -> 4 gates x 4 own pedestrians.
__device__ __forceinline__ void lstm2(int tid, Smem& s,
    const float (*Hin)[32], const float* __restrict__ bsum,
    const float* __restrict__ vx0, const float* __restrict__ vx1) {
  const int k = tid & 31, pg = tid >> 5, p0 = pg * 4;
  const float4* W0 = (const float4*)s.WL[k];
  const float4* W1 = (const float4*)s.WL[32 + k];
  const float4* W2 = (const float4*)s.WL[64 + k];
  const float4* W3 = (const float4*)s.WL[96 + k];
  const float v00 = vx0[k],      v01 = vx1[k];
  const float v10 = vx0[32 + k], v11 = vx1[32 + k];
  const float v20 = vx0[64 + k], v21 = vx1[64 + k];
  const float v30 = vx0[96 + k], v31 = vx1[96 + k];
  const float b0 = bsum[k], b1 = bsum[32 + k], b2 = bsum[64 + k], b3 = bsum[96 + k];
  float a0[4], a1[4], a2[4], a3[4];
  #pragma unroll
  for (int pi = 0; pi < 4; ++pi) {
    const int p = p0 + pi;
    const float x0 = s.Xprev[p][0], x1 = s.Xprev[p][1];
    a0[pi] = b0 + x0 * v00 + x1 * v01;
    a1[pi] = b1 + x0 * v10 + x1 * v11;
    a2[pi] = b2 + x0 * v20 + x1 * v21;
    a3[pi] = b3 + x0 * v30 + x1 * v31;
  }
  #pragma unroll
  for (int m4 = 0; m4 < 8; ++m4) {
    float4 w0 = W0[m4], w1 = W1[m4], w2 = W2[m4], w3 = W3[m4];
    #pragma unroll
    for (int pi = 0; pi < 4; ++pi) {
      float4 hv = ((const float4*)Hin[p0 + pi])[m4];
      a0[pi] += hv.x * w0.x + hv.y * w0.y + hv.z * w0.z + hv.w * w0.w;
      a1[pi] += hv.x * w1.x + hv.y * w1.y + hv.z * w1.z + hv.w * w1.w;
      a2[pi] += hv.x * w2.x + hv.y * w2.y + hv.z * w2.z + hv.w * w2.w;
      a3[pi] += hv.x * w3.x + hv.y * w3.y + hv.z * w3.z + hv.w * w3.w;
    }
  }
  #pragma unroll
  for (int pi = 0; pi < 4; ++pi) {
    const int p = p0 + pi;
    float iv = sigm(a0[pi]), fv = sigm(a1[pi]);
    float gv = ftanh(a2[pi]), ov = sigm(a3[pi]);
    float cn = fv * s.C[p][k] + iv * gv;
    s.C[p][k] = cn;
    s.HC[p][k] = ov * ftanh(cn);
  }
}

__global__ __launch_bounds__(BDIM, 2) void traj_fwd(
    const float* __restrict__ gx, const float* __restrict__ gdmat,
    const float* __restrict__ gbmat, const float* __restrict__ ghmat,
    const float* __restrict__ gimask,
    const float* __restrict__ gmean, const float* __restrict__ gvar,
    const float* __restrict__ gWemb, const float* __restrict__ gbemb,
    const float* __restrict__ gWihE, const float* __restrict__ gWhhE,
    const float* __restrict__ gbihE, const float* __restrict__ gbhhE,
    const float* __restrict__ gWihD, const float* __restrict__ gWhhD,
    const float* __restrict__ gbihD, const float* __restrict__ gbhhD,
    const float* __restrict__ gdom, const float* __restrict__ gWtemp,
    const float* __restrict__ gbtemp, const float* __restrict__ gWout,
    const float* __restrict__ gbout, float* __restrict__ gout)
{
  __shared__ Smem s;
  const int b = blockIdx.x, tid = threadIdx.x;

  // ================= PROLOGUE (one barrier) =================
  if (tid < 128) {   // E-fold: Vx = Wih.Wemb[:,f], bias += Wih.bemb
    float be = 0, bd = 0, e0 = 0, e1 = 0, d0 = 0, d1 = 0;
    #pragma unroll
    for (int k = 0; k < 16; ++k) {
      const float wE = gWihE[tid * 16 + k], wD = gWihD[tid * 16 + k];
      const float w0 = gWemb[k * 2 + 0], w1 = gWemb[k * 2 + 1], bb = gbemb[k];
      e0 += wE * w0; e1 += wE * w1; be += wE * bb;
      d0 += wD * w0; d1 += wD * w1; bd += wD * bb;
    }
    s.VxE0[tid] = e0; s.VxE1[tid] = e1;
    s.VxD0[tid] = d0; s.VxD1[tid] = d1;
    s.BsumE[tid] = gbihE[tid] + gbhhE[tid] + be;
    s.BsumD[tid] = gbihD[tid] + gbhhD[tid] + bd;
  }
  for (int i = tid; i < 2048; i += BDIM) {
    int kp = i >> 6, m = i & 63;
    s.WtTT[kp][m] = __float2bfloat16(gWtemp[i]);
  }
  for (int i = tid; i < 144; i += BDIM) s.Dom[i] = gdom[i];
  if (tid < 32) s.Btemp[tid] = gbtemp[tid];
  if (tid < 64) s.Wout[tid >> 5][tid & 31] = gWout[tid];
  if (tid < 2)  s.Bout[tid] = gbout[tid];
  if (tid < 4)  s.MV[tid] = (tid < 2) ? gmean[b * 2 + tid] : gvar[b * 2 + tid - 2];
  for (int i = tid; i < 512; i += BDIM) {
    int t = i >> 6, p = i & 63;
    s.MaskF[t][p] = gimask[(b * 64 + p) * 8 + t];
  }
  if (tid < 64) {
    const float4 m0 = *(const float4*)&gimask[(b * 64 + tid) * 8];
    const float4 m1 = *(const float4*)&gimask[(b * 64 + tid) * 8 + 4];
    unsigned int mb = 0;
    mb |= (m0.x > 0.0f) ? 1u : 0u;  mb |= (m0.y > 0.0f) ? 2u : 0u;
    mb |= (m0.z > 0.0f) ? 4u : 0u;  mb |= (m0.w > 0.0f) ? 8u : 0u;
    mb |= (m1.x > 0.0f) ? 16u : 0u; mb |= (m1.y > 0.0f) ? 32u : 0u;
    mb |= (m1.z > 0.0f) ? 64u : 0u; mb |= (m1.w > 0.0f) ? 128u : 0u;
    s.MaskBits[tid] = mb;
  }
  for (int idx = tid; idx < 128 * 32; idx += BDIM) {
    int j = idx >> 5, m = idx & 31;
    s.WL[j][m] = gWhhE[j * 32 + m];
  }
  for (int i = tid; i < 2048; i += BDIM) { s.H[0][i >> 5][i & 31] = 0.0f; s.C[i >> 5][i & 31] = 0.0f; }
  __syncthreads();

  bool uni = true;
  {
    const float d0 = s.Dom[0];
    for (int i = 0; i < 144; ++i) uni = uni && (s.Dom[i] == d0);
  }
  const float dom0 = s.Dom[0];

  // ================= ENCODER (2 barriers/iter) =================
  for (int t = 0; t < 8; ++t) {
    const int he = t & 1;
    {  // P1: W-build + rowsum shuffle + Xprev own-load
      const int i = tid >> 3, g = tid & 7, j8 = g * 8;
      const float mi = s.MaskF[t][i];
      const int gbase = (((b * 64 + i) * 8 + t) << 6) + j8;
      float w[8];
      if (uni) {
        const float4 dv0 = *(const float4*)&gdmat[gbase];
        const float4 dv1 = *(const float4*)&gdmat[gbase + 4];
        w[0] = fmaxf(dom0 - dv0.x, 0.0f) * mi * s.MaskF[t][j8 + 0];
        w[1] = fmaxf(dom0 - dv0.y, 0.0f) * mi * s.MaskF[t][j8 + 1];
        w[2] = fmaxf(dom0 - dv0.z, 0.0f) * mi * s.MaskF[t][j8 + 2];
        w[3] = fmaxf(dom0 - dv0.w, 0.0f) * mi * s.MaskF[t][j8 + 3];
        w[4] = fmaxf(dom0 - dv1.x, 0.0f) * mi * s.MaskF[t][j8 + 4];
        w[5] = fmaxf(dom0 - dv1.y, 0.0f) * mi * s.MaskF[t][j8 + 5];
        w[6] = fmaxf(dom0 - dv1.z, 0.0f) * mi * s.MaskF[t][j8 + 6];
        w[7] = fmaxf(dom0 - dv1.w, 0.0f) * mi * s.MaskF[t][j8 + 7];
      } else {
        #pragma unroll
        for (int c = 0; c < 8; ++c) {
          int gi = gbase + c;
          float dv = gdmat[gi], bv = gbmat[gi], hv = ghmat[gi];
          int ibn = (int)floorf(bv * (1.0f / 30.0f)); ibn = ibn < 0 ? 0 : (ibn > 11 ? 11 : ibn);
          int ihn = (int)floorf(hv * (1.0f / 30.0f)); ihn = ihn < 0 ? 0 : (ihn > 11 ? 11 : ihn);
          w[c] = fmaxf(s.Dom[ihn * 12 + ibn] - dv, 0.0f) * mi * s.MaskF[t][j8 + c];
        }
      }
      *(float4*)&s.W[i][j8]     = make_float4(w[0], w[1], w[2], w[3]);
      *(float4*)&s.W[i][j8 + 4] = make_float4(w[4], w[5], w[6], w[7]);
      float tot = ((w[0] + w[1]) + (w[2] + w[3])) + ((w[4] + w[5]) + (w[6] + w[7]));
      tot += __shfl_xor(tot, 1); tot += __shfl_xor(tot, 2); tot += __shfl_xor(tot, 4);
      if (g == 0) {
        s.RS[i] = 1.0f / (tot + 1e-8f);
        s.Xprev[i][0] = gx[((b * 64 + i) * 8 + t) * 2];
        s.Xprev[i][1] = gx[((b * 64 + i) * 8 + t) * 2 + 1];
      }
    }
    lstm2(tid, s, s.H[he], s.BsumE, s.VxE0, s.VxE1);
    __syncthreads();   // barA: HC all-rows visible to P3
    {  // P3: spatial attention + tanh -> H[he^1] own rows + Enc[t]
      const int k2 = tid & 31, ig = tid >> 5, i0 = ig * 4;
      float acc[4] = {};
      #pragma unroll
      for (int c = 0; c < 16; ++c) {
        float h0 = s.HC[c * 4 + 0][k2], h1 = s.HC[c * 4 + 1][k2];
        float h2 = s.HC[c * 4 + 2][k2], h3 = s.HC[c * 4 + 3][k2];
        #pragma unroll
        for (int ii = 0; ii < 4; ++ii) {
          float4 wv = *(const float4*)&s.W[i0 + ii][c * 4];
          acc[ii] += wv.x * h0 + wv.y * h1 + wv.z * h2 + wv.w * h3;
        }
      }
      #pragma unroll
      for (int ii = 0; ii < 4; ++ii) {
        int i = i0 + ii;
        float v = ftanh(acc[ii] * s.RS[i]);
        s.H[he ^ 1][i][k2] = v;
        s.Enc[t][i * 33 + k2] = v;
      }
    }
    __syncthreads();   // barB: HC-all-reads done before next P2 writes HC
  }

  // ================= DECODER START =================
  for (int idx = tid; idx < 128 * 32; idx += BDIM) {
    int j = idx >> 5, m = idx & 31;
    s.WL[j][m] = gWhhD[j * 32 + m];
  }
  for (int i = tid; i < 2048; i += BDIM) s.C[i >> 5][i & 31] = 0.0f;
  if (tid < 128) {
    int p = tid >> 1, f = tid & 1;
    s.Xprev[p][f] = gx[((b * 64 + p) * 8 + 7) * 2 + f];
  }
  __syncthreads();
  // W/RS persist from encoder t=7; h_enc is in H[0].

  // ================= DECODER (1 barrier/step on fast path) =================
  for (int sd = 0; sd < 12; ++sd) {
    const int cur = sd & 1;
    {  // A: spatial attn on H[cur] -> Emb own rows
      const int k2 = tid & 31, ig = tid >> 5, i0 = ig * 4;
      float acc[4] = {};
      #pragma unroll
      for (int c = 0; c < 16; ++c) {
        float h0 = s.H[cur][c * 4 + 0][k2], h1 = s.H[cur][c * 4 + 1][k2];
        float h2 = s.H[cur][c * 4 + 2][k2], h3 = s.H[cur][c * 4 + 3][k2];
        #pragma unroll
        for (int ii = 0; ii < 4; ++ii) {
          float4 wv = *(const float4*)&s.W[i0 + ii][c * 4];
          acc[ii] += wv.x * h0 + wv.y * h1 + wv.z * h2 + wv.w * h3;
        }
      }
      #pragma unroll
      for (int ii = 0; ii < 4; ++ii)
        s.u.EmbCtx[i0 + ii][k2] = ftanh(acc[ii] * s.RS[i0 + ii]);
    }
    lstm2(tid, s, s.u.EmbCtx, s.BsumD, s.VxD0, s.VxD1);
    {  // temporal: thread = (p = tid>>3 own, t8 = tid&7)
      const int p = tid >> 3, t8 = tid & 7;
      const float4* h4p = (const float4*)s.HC[p];   // 144B rows: 16B-aligned
      const float* enr = &s.Enc[t8][p * 33];
      float sc = 0.0f;
      #pragma unroll
      for (int c = 0; c < 8; ++c) {
        const float4 h4 = h4p[c];
        sc += h4.x * enr[c * 4 + 0] + h4.y * enr[c * 4 + 1]
            + h4.z * enr[c * 4 + 2] + h4.w * enr[c * 4 + 3];
      }
      sc *= 0.17677669529663687f;
      sc = ((s.MaskBits[p] >> t8) & 1u) ? sc : -1e9f;
      float mx = sc;
      mx = fmaxf(mx, __shfl_xor(mx, 1));
      mx = fmaxf(mx, __shfl_xor(mx, 2));
      mx = fmaxf(mx, __shfl_xor(mx, 4));
      float e = __expf(sc - mx);
      float den = e;
      den += __shfl_xor(den, 1);
      den += __shfl_xor(den, 2);
      den += __shfl_xor(den, 4);
      float a = e / den;
      float av[8];
      #pragma unroll
      for (int tt = 0; tt < 8; ++tt) av[tt] = __shfl(a, tt, 8);
      const int kb = t8 * 4;
      float c0 = 0, c1 = 0, c2 = 0, c3 = 0;
      #pragma unroll
      for (int tt = 0; tt < 8; ++tt) {
        const float* er = &s.Enc[tt][p * 33 + kb];
        c0 += av[tt] * er[0]; c1 += av[tt] * er[1];
        c2 += av[tt] * er[2]; c3 += av[tt] * er[3];
      }
      *(float4*)&s.u.EmbCtx[p][kb] = make_float4(c0, c1, c2, c3);
    }
    {  // wtemp + fused x_out
      const int kp = tid & 31, pg = tid >> 5;
      const uint2* wrow = (const uint2*)s.WtTT[kp];
      float acc[4];
      #pragma unroll
      for (int pi = 0; pi < 4; ++pi) acc[pi] = s.Btemp[kp];
      #pragma unroll
      for (int mc = 0; mc < 16; ++mc) {
        const uint2 w2 = wrow[mc];
        const float f0 = __uint_as_float(w2.x << 16);
        const float f1 = __uint_as_float(w2.x & 0xFFFF0000u);
        const float f2 = __uint_as_float(w2.y << 16);
        const float f3 = __uint_as_float(w2.y & 0xFFFF0000u);
        #pragma unroll
        for (int pi = 0; pi < 4; ++pi) {
          const int p = pg * 4 + pi;
          const float4 av = (mc < 8) ? *(const float4*)&s.u.EmbCtx[p][mc * 4]
                                     : *(const float4*)&s.HC[p][(mc - 8) * 4];
          acc[pi] += av.x * f0 + av.y * f1 + av.z * f2 + av.w * f3;
        }
      }
      float r0[4], r1[4];
      #pragma unroll
      for (int pi = 0; pi < 4; ++pi) {
        float hv = ftanh(acc[pi]);
        s.H[cur ^ 1][pg * 4 + pi][kp] = hv;
        r0[pi] = hv * s.Wout[0][kp];
        r1[pi] = hv * s.Wout[1][kp];
      }
      #pragma unroll
      for (int st = 1; st < 32; st <<= 1) {
        #pragma unroll
        for (int pi = 0; pi < 4; ++pi) {
          r0[pi] += __shfl_xor(r0[pi], st);
          r1[pi] += __shfl_xor(r1[pi], st);
        }
      }
      if (kp == 0) {
        const int p0 = pg * 4;
        float* go = &gout[((b * 64 + p0) * 12 + sd) * 2];
        #pragma unroll
        for (int pi = 0; pi < 4; ++pi) {
          float vx = ftanh(r0[pi] + s.Bout[0]);
          float vy = ftanh(r1[pi] + s.Bout[1]);
          s.Xout[cur][p0 + pi][0] = vx; s.Xout[cur][p0 + pi][1] = vy;
          go[pi * 24] = vx; go[pi * 24 + 1] = vy;
        }
      }
    }
    __syncthreads();   // bar1: Xout[cur] + H[cur^1] visible to all
    if (sd < 11) {
      if (uni) {
        const int i = tid >> 3, g = tid & 7, j8 = g * 8;
        const float v0 = s.MV[2], v1 = s.MV[3];
        const float xi0 = s.Xout[cur][i][0], xi1 = s.Xout[cur][i][1];
        const float mi = s.MaskF[7][i];
        float w[8];
        #pragma unroll
        for (int c = 0; c < 8; ++c) {
          const int j = j8 + c;
          float rx = (s.Xout[cur][j][0] - xi0) * v0;
          float ry = (s.Xout[cur][j][1] - xi1) * v1;
          float dist = sqrtf(rx * rx + ry * ry + 1e-12f);
          w[c] = fmaxf(dom0 - dist, 0.0f) * mi * s.MaskF[7][j];
        }
        *(float4*)&s.W[i][j8]     = make_float4(w[0], w[1], w[2], w[3]);
        *(float4*)&s.W[i][j8 + 4] = make_float4(w[4], w[5], w[6], w[7]);
        float tot = ((w[0] + w[1]) + (w[2] + w[3])) + ((w[4] + w[5]) + (w[6] + w[7]));
        tot += __shfl_xor(tot, 1); tot += __shfl_xor(tot, 2); tot += __shfl_xor(tot, 4);
        if (g == 0) {
          s.RS[i] = 1.0f / (tot + 1e-8f);
          s.Xprev[i][0] = s.Xout[cur][i][0];
          s.Xprev[i][1] = s.Xout[cur][i][1];
        }
      } else {
        if (tid < 64) {
          const int p = tid;
          float m0 = s.MV[0], m1 = s.MV[1], v0 = s.MV[2], v1 = s.MV[3];
          float px = s.Xout[cur][p][0] * v0 + m0, py = s.Xout[cur][p][1] * v1 + m1;
          float qx = s.Xprev[p][0] * v0 + m0, qy = s.Xprev[p][1] * v1 + m1;
          s.u.sp.Head[p] = mod360(atan2_deg(py - qy, px - qx));
          s.u.sp.Pos[p][0] = px; s.u.sp.Pos[p][1] = py;
        }
        __syncthreads();
        const int i = tid >> 3, g = tid & 7, j8 = g * 8;
        const float mi = s.MaskF[7][i], hi = s.u.sp.Head[i];
        const float pix = s.u.sp.Pos[i][0], piy = s.u.sp.Pos[i][1];
        float w[8];
        #pragma unroll
        for (int c = 0; c < 8; ++c) {
          const int j = j8 + c;
          float rx = s.u.sp.Pos[j][0] - pix;
          float ry = s.u.sp.Pos[j][1] - piy;
          float dist = sqrtf(rx * rx + ry * ry + 1e-12f);
          float rb = mod360(atan2_deg(ry, rx) - hi);
          float rh = mod360(s.u.sp.Head[j] - hi);
          int ibn = (int)floorf(rb * (1.0f / 30.0f)); ibn = ibn < 0 ? 0 : (ibn > 11 ? 11 : ibn);
          int ihn = (int)floorf(rh * (1.0f / 30.0f)); ihn = ihn < 0 ? 0 : (ihn > 11 ? 11 : ihn);
          w[c] = fmaxf(s.Dom[ihn * 12 + ibn] - dist, 0.0f) * mi * s.MaskF[7][j];
        }
        *(float4*)&s.W[i][j8]     = make_float4(w[0], w[1], w[2], w[3]);
        *(float4*)&s.W[i][j8 + 4] = make_float4(w[4], w[5], w[6], w[7]);
        float tot = ((w[0] + w[1]) + (w[2] + w[3])) + ((w[4] + w[5]) + (w[6] + w[7]));
        tot += __shfl_xor(tot, 1); tot += __shfl_xor(tot, 2); tot += __shfl_xor(tot, 4);
        if (g == 0) {
          s.RS[i] = 1.0f / (tot + 1e-8f);
          s.Xprev[i][0] = s.Xout[cur][i][0];
          s.Xprev[i][1] = s.Xout[cur][i][1];
        }
        __syncthreads();
      }
    }
  }
}

extern "C" void kernel_launch(void* const* d_in, const int* in_sizes, int n_in,
                              void* d_out, int out_size, void* d_ws, size_t ws_size,
                              hipStream_t stream) {
  (void)in_sizes; (void)n_in; (void)d_ws; (void)ws_size; (void)out_size;
  traj_fwd<<<512, BDIM, 0, stream>>>(
      (const float*)d_in[0], (const float*)d_in[1], (const float*)d_in[2],
      (const float*)d_in[3], (const float*)d_in[4],
      /* d_in[5] output_mask, d_in[6] scene unused */
      (const float*)d_in[7], (const float*)d_in[8],
      (const float*)d_in[9], (const float*)d_in[10],
      (const float*)d_in[11], (const float*)d_in[12],
      (const float*)d_in[13], (const float*)d_in[14],
      (const float*)d_in[15], (const float*)d_in[16],
      (const float*)d_in[17], (const float*)d_in[18],
      (const float*)d_in[19], (const float*)d_in[20],
      (const float*)d_in[21], (const float*)d_in[22], (const float*)d_in[23],
      (float*)d_out);
}